// Round 16
// baseline (405.269 us; speedup 1.0000x reference)
//
#include <hip/hip_runtime.h>
#include <math.h>

#define DIM 512
#define NP  64
#define TAU 4.5e-4f        // gap34 flag threshold (6.4 sigma of single-bf16-B gap err)
#define LISTCAP 32768
#define RFB 256

// workspace layout (bytes)
#define WS_PTW   0          // float[512][64] raw transposed protos   (131072)
#define WS_BHI   131072     // ushort frag-linear bf16 [16][4][64][8] (65536)
#define WS_INV64 196608     // double[64]                             (512)
#define WS_CNT   197120     // int (+pad)                             (128)
#define WS_LIST  197248     // int[LISTCAP]                           (131072)
#define WS_WI    328320     // float4[65536] weights+indices          (1048576)

typedef __attribute__((ext_vector_type(8))) short bf16x8;
typedef __attribute__((ext_vector_type(4))) float f32x4;

__device__ __forceinline__ unsigned short f2bf(float f) {   // RNE fp32->bf16
  const unsigned int u = __float_as_uint(f);
  return (unsigned short)((u + 0x7FFFu + ((u >> 16) & 1u)) >> 16);
}
__device__ __forceinline__ float bf2f(unsigned short h) {
  return __uint_as_float(((unsigned int)h) << 16);
}

__device__ __forceinline__ void gload_lds16(const void* g, void* l) {
  __builtin_amdgcn_global_load_lds(
      (const __attribute__((address_space(1))) void*)g,
      (__attribute__((address_space(3))) void*)l, 16, 0, 0);
}

__device__ __forceinline__ void ins4f(float v, int idx, float& v0, float& v1,
                                      float& v2, float& v3, int& j0, int& j1,
                                      int& j2, int& j3) {
  const bool b0 = v > v0, b1 = v > v1, b2 = v > v2, b3 = v > v3;
  v3 = b2 ? v2 : (b3 ? v : v3);  j3 = b2 ? j2 : (b3 ? idx : j3);
  v2 = b1 ? v1 : (b2 ? v : v2);  j2 = b1 ? j1 : (b2 ? idx : j2);
  v1 = b0 ? v0 : (b1 ? v : v1);  j1 = b0 ? j0 : (b1 ? idx : j1);
  v0 = b0 ? v  : v0;             j0 = b0 ? idx : j0;
}

__device__ __forceinline__ void ins3d(double v, int idx, double& b0, double& b1,
                                      double& b2, int& k0, int& k1, int& k2) {
  const bool c0 = v > b0, c1 = v > b1, c2 = v > b2;
  b2 = c1 ? b1 : (c2 ? v : b2);  k2 = c1 ? k1 : (c2 ? idx : k2);
  b1 = c0 ? b0 : (c1 ? v : b1);  k1 = c0 ? k0 : (c1 ? idx : k1);
  b0 = c0 ? v  : b0;             k0 = c0 ? idx : k0;
}

// ---------------------------------------------------------------------------
// Kernel 1: transpose protos -> ptw[k][p]; fp64 inverse norms; zero cnt.
// ---------------------------------------------------------------------------
__global__ __launch_bounds__(256) void prep_kernel(
    const float* __restrict__ protos, float* __restrict__ ptw,
    double* __restrict__ inv64, int* __restrict__ cnt) {
  if (blockIdx.x == 0 && threadIdx.x == 0) *cnt = 0;
  const int p = (blockIdx.x * 256 + threadIdx.x) >> 6;
  const int lane = threadIdx.x & 63;
  if (p >= NP) return;
  const float4* pr = (const float4*)(protos + (size_t)p * DIM);
  const float4 a = pr[lane * 2];
  const float4 b = pr[lane * 2 + 1];
  double ss = (double)a.x * a.x + (double)a.y * a.y + (double)a.z * a.z +
              (double)a.w * a.w + (double)b.x * b.x + (double)b.y * b.y +
              (double)b.z * b.z + (double)b.w * b.w;
#pragma unroll
  for (int m = 1; m < 64; m <<= 1) ss += __shfl_xor(ss, m);
  const double inv = 1.0 / fmax(sqrt(ss), 1e-12);
  if (lane == 0) inv64[p] = inv;
  const float v[8] = {a.x, a.y, a.z, a.w, b.x, b.y, b.z, b.w};
#pragma unroll
  for (int e = 0; e < 8; ++e)
    ptw[(size_t)(lane * 8 + e) * NP + p] = v[e];
}

// ---------------------------------------------------------------------------
// Kernel 2: build B fragments (single RNE bf16 of normalized protos).
// Fragment (ks,pt,lane,e) = p_hat[pt*16+(lane&15)][ks*32+(lane>>4)*8+e].
// ---------------------------------------------------------------------------
__global__ __launch_bounds__(64) void prep_frag_kernel(
    const float* __restrict__ protos, const double* __restrict__ inv64,
    unsigned short* __restrict__ bhi) {
  const int ks = blockIdx.x >> 2;
  const int pt = blockIdx.x & 3;
  const int l = threadIdx.x;
  const int p = pt * 16 + (l & 15);
  const int k0 = ks * 32 + (l >> 4) * 8;
  const double inv = inv64[p];
  const size_t base = ((size_t)(ks * 4 + pt) * 64 + l) * 8;
#pragma unroll
  for (int e = 0; e < 8; ++e) {
    const float v = (float)((double)protos[(size_t)p * DIM + k0 + e] * inv);
    bhi[base + e] = f2bf(v);
  }
}

// ---------------------------------------------------------------------------
// Kernel 3: MFMA sim -> top4 -> softmax weights (no gather).
// 256 thr = 4 waves. Wave wid: ALL 64 rows x protos [wid*16, wid*16+16).
// Full B preloaded: 16 frags = 64 VGPR -> k-loop VMEM = 2 A-requests/chunk.
// A: shared depth-4 LDS ring, T4 discipline (vmcnt(4) -> s_barrier ->
// stage c+3), XOR-granule source swizzle, swizzled ds_read_b128.
// A split hi/lo in VALU; 2 MFMA per rg per chunk (Ahi*B + Alo*B).
// ---------------------------------------------------------------------------
__global__ __launch_bounds__(256) void sim_kernel(
    const float* __restrict__ query, const unsigned short* __restrict__ bhi_u,
    float4* __restrict__ wi_g, int* __restrict__ cnt, int* __restrict__ list) {
  __shared__ __align__(16) float Abuf[4][64 * 32];   // 32 KiB ring [buf][64r x 32k]
  __shared__ float4 topV[4][64];
  __shared__ int4   topJ[4][64];
  __shared__ float  ssS[64];

  const int t = threadIdx.x;
  const int wid = t >> 6;
  const int l = t & 63;
  const int lr = l & 15;          // D col: proto within wave tile; A row idx
  const int lg = l >> 4;          // k-group; D row group
  const int row0 = blockIdx.x * 64;

  // ---- full B preload: wave wid's 16 proto-frags, all 16 chunks ----
  const bf16x8* bhp = (const bf16x8*)bhi_u;
  bf16x8 Bf[16];
#pragma unroll
  for (int c = 0; c < 16; ++c)
    Bf[c] = bhp[(size_t)(c * 4 + wid) * 64 + l];

  // ---- staging: wave wid stages rows wid*16..wid*16+15 (2 instrs/chunk) ----
  const int sgswz = ((l & 7) ^ (l >> 3)) << 4;   // swizzled source granule
  auto stage = [&](int cc) {
#pragma unroll
    for (int i = 0; i < 2; ++i) {
      const char* src = (const char*)query +
          (size_t)(row0 + wid * 16 + i * 8 + (l >> 3)) * 2048 + cc * 128 + sgswz;
      gload_lds16(src, (char*)&Abuf[cc & 3][0] + (wid * 16 + i * 8) * 128);
    }
  };

  f32x4 acc[4] = {};
  float ss[4] = {0.f, 0.f, 0.f, 0.f};

  stage(0); stage(1); stage(2);    // 6 A-requests in flight
  const int g0 = lg * 2;
  const int sw = lr & 7;

#define SIM_CHUNK(C, NV)                                                      \
  {                                                                           \
    asm volatile("s_waitcnt vmcnt(" #NV ")" ::: "memory");                    \
    __builtin_amdgcn_sched_barrier(0);                                        \
    __builtin_amdgcn_s_barrier();                                             \
    if ((C) + 3 < 16) stage((C) + 3);                                         \
    const char* ab = (const char*)&Abuf[(C) & 3][0];                          \
    _Pragma("unroll")                                                         \
    for (int rg = 0; rg < 4; ++rg) {                                          \
      const int rl = rg * 16 + lr;                                            \
      const float4 a0 = *(const float4*)(ab + rl * 128 + ((g0 ^ sw) << 4));   \
      const float4 a1 = *(const float4*)(ab + rl * 128 + (((g0 + 1) ^ sw) << 4)); \
      const float av[8] = {a0.x, a0.y, a0.z, a0.w, a1.x, a1.y, a1.z, a1.w};   \
      bf16x8 ahi, alo;                                                        \
      _Pragma("unroll")                                                       \
      for (int i = 0; i < 8; ++i) {                                           \
        const unsigned int u = __float_as_uint(av[i]);                        \
        const unsigned short h = (unsigned short)(u >> 16);                   \
        ahi[i] = (short)h;                                                    \
        alo[i] = (short)f2bf(av[i] - bf2f(h));                                \
        ss[rg] += av[i] * av[i];                                              \
      }                                                                       \
      acc[rg] = __builtin_amdgcn_mfma_f32_16x16x32_bf16(ahi, Bf[(C)], acc[rg], 0, 0, 0); \
      acc[rg] = __builtin_amdgcn_mfma_f32_16x16x32_bf16(alo, Bf[(C)], acc[rg], 0, 0, 0); \
    }                                                                         \
  }

  SIM_CHUNK(0, 4)  SIM_CHUNK(1, 4)  SIM_CHUNK(2, 4)  SIM_CHUNK(3, 4)
  SIM_CHUNK(4, 4)  SIM_CHUNK(5, 4)  SIM_CHUNK(6, 4)  SIM_CHUNK(7, 4)
  SIM_CHUNK(8, 4)  SIM_CHUNK(9, 4)  SIM_CHUNK(10, 4) SIM_CHUNK(11, 4)
  SIM_CHUNK(12, 4) SIM_CHUNK(13, 4) SIM_CHUNK(14, 2) SIM_CHUNK(15, 0)
#undef SIM_CHUNK

  // combine k-groups: lane l then holds full sumsq of rows rg*16 + (l&15)
#pragma unroll
  for (int rg = 0; rg < 4; ++rg) {
    ss[rg] += __shfl_xor(ss[rg], 16);
    ss[rg] += __shfl_xor(ss[rg], 32);
  }
  if (wid == 0 && l < 16) {
#pragma unroll
    for (int rg = 0; rg < 4; ++rg) ssS[rg * 16 + l] = ss[rg];
  }

  // ---- per-wave top4 of its 16 protos, per row ----
  // D layout: acc[rg][e] = sim(row rg*16 + lg*4 + e, proto wid*16 + lr)
#pragma unroll
  for (int rg = 0; rg < 4; ++rg) {
#pragma unroll
    for (int e = 0; e < 4; ++e) {
      float v0 = acc[rg][e], v1 = -1e30f, v2 = -1e30f, v3 = -1e30f;
      int j0 = wid * 16 + lr, j1 = 0, j2 = 0, j3 = 0;
#pragma unroll
      for (int m = 1; m <= 8; m <<= 1) {   // butterfly within 16-lane group
        const float p0 = __shfl_xor(v0, m), p1 = __shfl_xor(v1, m);
        const float p2 = __shfl_xor(v2, m), p3 = __shfl_xor(v3, m);
        const int q0 = __shfl_xor(j0, m), q1 = __shfl_xor(j1, m);
        const int q2 = __shfl_xor(j2, m), q3 = __shfl_xor(j3, m);
        ins4f(p0, q0, v0, v1, v2, v3, j0, j1, j2, j3);
        ins4f(p1, q1, v0, v1, v2, v3, j0, j1, j2, j3);
        ins4f(p2, q2, v0, v1, v2, v3, j0, j1, j2, j3);
        ins4f(p3, q3, v0, v1, v2, v3, j0, j1, j2, j3);
      }
      if (lr == 0) {
        const int r = rg * 16 + lg * 4 + e;
        topV[wid][r] = make_float4(v0, v1, v2, v3);
        topJ[wid][r] = make_int4(j0, j1, j2, j3);
      }
    }
  }
  __syncthreads();

  // ---- merge 4 waves' top4 -> final top4, softmax, flag (wave 0) ----
  if (wid == 0) {
    const int r = l;
    float v0 = -1e30f, v1 = -1e30f, v2 = -1e30f, v3 = -1e30f;
    int j0 = 0, j1 = 0, j2 = 0, j3 = 0;
#pragma unroll
    for (int w = 0; w < 4; ++w) {
      const float4 tv = topV[w][r];
      const int4 tj = topJ[w][r];
      ins4f(tv.x, tj.x, v0, v1, v2, v3, j0, j1, j2, j3);
      ins4f(tv.y, tj.y, v0, v1, v2, v3, j0, j1, j2, j3);
      ins4f(tv.z, tj.z, v0, v1, v2, v3, j0, j1, j2, j3);
      ins4f(tv.w, tj.w, v0, v1, v2, v3, j0, j1, j2, j3);
    }
    const float qi = 1.0f / fmaxf(sqrtf(ssS[r]), 1e-12f);
    const float s0 = v0 * qi, s1 = v1 * qi, s2 = v2 * qi, s3 = v3 * qi;
    const float e1 = expf(s1 - s0), e2 = expf(s2 - s0);
    const float inv = 1.0f / (1.0f + e1 + e2);
    wi_g[row0 + r] = make_float4(inv, e1 * inv, e2 * inv,
                                 __int_as_float(j0 | (j1 << 6) | (j2 << 12)));
    if (s2 - s3 < TAU) {
      const int pos = atomicAdd(cnt, 1);
      if (pos < LISTCAP) list[pos] = row0 + r;
    }
  }
}

// ---------------------------------------------------------------------------
// Kernel 4: pure gather. 2048 blocks x 4 waves; wave handles 8 rows.
// ---------------------------------------------------------------------------
__global__ __launch_bounds__(256) void gather_kernel(
    const float* __restrict__ protos, const float4* __restrict__ wi_g,
    float* __restrict__ out) {
  const int l = threadIdx.x & 63;
  const int gw = blockIdx.x * 4 + (threadIdx.x >> 6);
  const int base = gw * 8;
#pragma unroll 2
  for (int r = 0; r < 8; ++r) {
    const int row = base + r;
    const float4 wi = wi_g[row];
    const int pack = __float_as_int(wi.w);
    const int i0 = pack & 63, i1 = (pack >> 6) & 63, i2 = (pack >> 12) & 63;
    const float* p0 = protos + (size_t)i0 * DIM;
    const float* p1 = protos + (size_t)i1 * DIM;
    const float* p2 = protos + (size_t)i2 * DIM;
    float* orow = out + (size_t)row * DIM;
#pragma unroll
    for (int h = 0; h < 2; ++h) {
      const int col = h * 256 + l * 4;
      const float4 x = *(const float4*)(p0 + col);
      const float4 y = *(const float4*)(p1 + col);
      const float4 z = *(const float4*)(p2 + col);
      float4 res;
      res.x = wi.x * x.x + wi.y * y.x + wi.z * z.x;
      res.y = wi.x * x.y + wi.y * y.y + wi.z * z.y;
      res.z = wi.x * x.z + wi.y * y.z + wi.z * z.z;
      res.w = wi.x * x.w + wi.y * y.w + wi.z * z.w;
      *(float4*)(orow + col) = res;
    }
  }
}

// ---------------------------------------------------------------------------
// Kernel 5: fp64 refine of compacted near-tie rows. One wave per row.
// ---------------------------------------------------------------------------
__global__ __launch_bounds__(256) void refine_kernel(
    const float* __restrict__ query, const float* __restrict__ protos,
    const float* __restrict__ ptw, const double* __restrict__ inv64,
    const int* __restrict__ cnt, const int* __restrict__ list,
    float* __restrict__ out) {
  const int n = min(*cnt, LISTCAP);
  const int lane = threadIdx.x & 63;
  const int gw = blockIdx.x * 4 + (threadIdx.x >> 6);

  for (int i = gw; i < n; i += RFB * 4) {
    const int row = list[i];
    const float* q = query + (size_t)row * DIM;
    double a0 = 0.0, a1 = 0.0, a2 = 0.0, a3 = 0.0;
    float qs = 0.f;
#pragma unroll 4
    for (int k = 0; k < DIM; k += 4) {
      const float4 qv = *(const float4*)(q + k);
      a0 = fma((double)qv.x, (double)ptw[(size_t)(k + 0) * NP + lane], a0);
      a1 = fma((double)qv.y, (double)ptw[(size_t)(k + 1) * NP + lane], a1);
      a2 = fma((double)qv.z, (double)ptw[(size_t)(k + 2) * NP + lane], a2);
      a3 = fma((double)qv.w, (double)ptw[(size_t)(k + 3) * NP + lane], a3);
      qs += qv.x * qv.x + qv.y * qv.y + qv.z * qv.z + qv.w * qv.w;
    }
    const double sim = (a0 + a1 + a2 + a3) * inv64[lane];

    double b0 = sim, b1 = -1e300, b2 = -1e300;
    int k0 = lane, k1 = 0, k2 = 0;
#pragma unroll
    for (int m = 1; m <= 32; m <<= 1) {
      const double p0 = __shfl_xor(b0, m), p1 = __shfl_xor(b1, m),
                   p2 = __shfl_xor(b2, m);
      const int q0 = __shfl_xor(k0, m), q1 = __shfl_xor(k1, m),
                q2 = __shfl_xor(k2, m);
      ins3d(p0, q0, b0, b1, b2, k0, k1, k2);
      ins3d(p1, q1, b0, b1, b2, k0, k1, k2);
      ins3d(p2, q2, b0, b1, b2, k0, k1, k2);
    }
    const double qi = 1.0 / fmax(sqrt((double)qs), 1e-12);
    const double s0 = b0 * qi, s1 = b1 * qi, s2 = b2 * qi;
    const double e1 = exp(s1 - s0), e2 = exp(s2 - s0);
    const double inv = 1.0 / (1.0 + e1 + e2);
    const double w0 = inv, w1 = e1 * inv, w2 = e2 * inv;
    const float* p0r = protos + (size_t)k0 * DIM;
    const float* p1r = protos + (size_t)k1 * DIM;
    const float* p2r = protos + (size_t)k2 * DIM;
#pragma unroll
    for (int u = 0; u < 2; ++u) {
      const int col = u * 256 + lane * 4;
      const float4 x = *(const float4*)(p0r + col);
      const float4 y = *(const float4*)(p1r + col);
      const float4 z = *(const float4*)(p2r + col);
      float4 res;
      res.x = (float)(w0 * x.x + w1 * y.x + w2 * z.x);
      res.y = (float)(w0 * x.y + w1 * y.y + w2 * z.y);
      res.z = (float)(w0 * x.z + w1 * y.z + w2 * z.z);
      res.w = (float)(w0 * x.w + w1 * y.w + w2 * z.w);
      *(float4*)(out + (size_t)row * DIM + col) = res;
    }
  }
}

extern "C" void kernel_launch(void* const* d_in, const int* in_sizes, int n_in,
                              void* d_out, int out_size, void* d_ws, size_t ws_size,
                              hipStream_t stream) {
  const float* query = (const float*)d_in[0];
  const float* protos = (const float*)d_in[1];
  float* out = (float*)d_out;
  float* ptw = (float*)((char*)d_ws + WS_PTW);
  unsigned short* bhi = (unsigned short*)((char*)d_ws + WS_BHI);
  double* inv64 = (double*)((char*)d_ws + WS_INV64);
  int* cnt = (int*)((char*)d_ws + WS_CNT);
  int* list = (int*)((char*)d_ws + WS_LIST);
  float4* wi_g = (float4*)((char*)d_ws + WS_WI);

  const int nrows = in_sizes[0] / DIM;

  hipLaunchKernelGGL(prep_kernel, dim3(16), dim3(256), 0, stream,
                     protos, ptw, inv64, cnt);
  hipLaunchKernelGGL(prep_frag_kernel, dim3(64), dim3(64), 0, stream,
                     protos, inv64, bhi);
  hipLaunchKernelGGL(sim_kernel, dim3(nrows / 64), dim3(256), 0, stream,
                     query, bhi, wi_g, cnt, list);
  hipLaunchKernelGGL(gather_kernel, dim3(nrows / 32), dim3(256), 0, stream,
                     protos, wi_g, out);
  hipLaunchKernelGGL(refine_kernel, dim3(RFB), dim3(256), 0, stream,
                     query, protos, ptw, inv64, cnt, list, out);
}

// Round 17
// 108.693 us; speedup vs baseline: 3.7286x; 3.7286x over previous
//
#include <hip/hip_runtime.h>
#include <math.h>

#define DIM 512
#define NP  64
#define TAU 4e-5f          // gap34 flag threshold (proven w/ hi-lo split)
#define LISTCAP 8192
#define RFB 128

// workspace layout (bytes)
#define WS_PTW   0          // float[512][64] raw transposed protos   (131072)
#define WS_BHI   131072     // ushort frag-linear bf16 hi [16][4][64][8] (65536)
#define WS_BLO   196608     // ushort frag-linear bf16 lo                (65536)
#define WS_INV64 262144     // double[64]                             (512)
#define WS_CNT   262656     // int (+pad)                             (128)
#define WS_LIST  262784     // int[LISTCAP]                           (32768)

typedef __attribute__((ext_vector_type(8))) short bf16x8;
typedef __attribute__((ext_vector_type(8))) unsigned short u16x8;
typedef __attribute__((ext_vector_type(4))) float f32x4;

__device__ __forceinline__ unsigned short f2bf(float f) {   // RNE fp32->bf16
  const unsigned int u = __float_as_uint(f);
  return (unsigned short)((u + 0x7FFFu + ((u >> 16) & 1u)) >> 16);
}
__device__ __forceinline__ float bf2f(unsigned short h) {
  return __uint_as_float(((unsigned int)h) << 16);
}

__device__ __forceinline__ void gload_lds16(const void* g, void* l) {
  __builtin_amdgcn_global_load_lds(
      (const __attribute__((address_space(1))) void*)g,
      (__attribute__((address_space(3))) void*)l, 16, 0, 0);
}

__device__ __forceinline__ void ins4f(float v, int idx, float& v0, float& v1,
                                      float& v2, float& v3, int& j0, int& j1,
                                      int& j2, int& j3) {
  const bool b0 = v > v0, b1 = v > v1, b2 = v > v2, b3 = v > v3;
  v3 = b2 ? v2 : (b3 ? v : v3);  j3 = b2 ? j2 : (b3 ? idx : j3);
  v2 = b1 ? v1 : (b2 ? v : v2);  j2 = b1 ? j1 : (b2 ? idx : j2);
  v1 = b0 ? v0 : (b1 ? v : v1);  j1 = b0 ? j0 : (b1 ? idx : j1);
  v0 = b0 ? v  : v0;             j0 = b0 ? idx : j0;
}

__device__ __forceinline__ void ins3d(double v, int idx, double& b0, double& b1,
                                      double& b2, int& k0, int& k1, int& k2) {
  const bool c0 = v > b0, c1 = v > b1, c2 = v > b2;
  b2 = c1 ? b1 : (c2 ? v : b2);  k2 = c1 ? k1 : (c2 ? idx : k2);
  b1 = c0 ? b0 : (c1 ? v : b1);  k1 = c0 ? k0 : (c1 ? idx : k1);
  b0 = c0 ? v  : b0;             k0 = c0 ? idx : k0;
}

// ---------------------------------------------------------------------------
// Kernel 1 (merged prep): each wave owns ONE prototype end-to-end:
// norm reduce -> inv64 + ptw row + its bf16 hi/lo fragment slice.
// Lane k-ownership (k0 = lane*8) maps onto fragment layout: ks=lane>>2,
// lg=lane&3, so lane writes ushort8 at ((ks*4+pt)*64 + lg*16 + lr)*8.
// Grid 16 x 256 threads (4 waves = 4 protos per block).
// ---------------------------------------------------------------------------
__global__ __launch_bounds__(256) void prep_all_kernel(
    const float* __restrict__ protos, float* __restrict__ ptw,
    unsigned short* __restrict__ bhi, unsigned short* __restrict__ blo,
    double* __restrict__ inv64, int* __restrict__ cnt) {
  if (blockIdx.x == 0 && threadIdx.x == 0) *cnt = 0;
  const int p = blockIdx.x * 4 + (threadIdx.x >> 6);
  const int lane = threadIdx.x & 63;
  const float4* pr = (const float4*)(protos + (size_t)p * DIM);
  const float4 a = pr[lane * 2];
  const float4 b = pr[lane * 2 + 1];
  double ss = (double)a.x * a.x + (double)a.y * a.y + (double)a.z * a.z +
              (double)a.w * a.w + (double)b.x * b.x + (double)b.y * b.y +
              (double)b.z * b.z + (double)b.w * b.w;
#pragma unroll
  for (int m = 1; m < 64; m <<= 1) ss += __shfl_xor(ss, m);
  const double inv = 1.0 / fmax(sqrt(ss), 1e-12);
  if (lane == 0) inv64[p] = inv;
  const float v[8] = {a.x, a.y, a.z, a.w, b.x, b.y, b.z, b.w};
  u16x8 hi8, lo8;
#pragma unroll
  for (int e = 0; e < 8; ++e) {
    ptw[(size_t)(lane * 8 + e) * NP + p] = v[e];
    const float vh = (float)((double)v[e] * inv);
    const unsigned short h = f2bf(vh);
    hi8[e] = h;
    lo8[e] = f2bf(vh - bf2f(h));
  }
  const int ks = lane >> 2, lg = lane & 3, pt = p >> 4, lr = p & 15;
  const size_t base = ((size_t)(ks * 4 + pt) * 64 + lg * 16 + lr) * 8;
  *(u16x8*)&bhi[base] = hi8;
  *(u16x8*)&blo[base] = lo8;
}

// ---------------------------------------------------------------------------
// Kernel 2: MFMA sim (split-bf16) -> top4 -> softmax -> gather (fused).
// 256 thr = 4 fully independent waves; ZERO barriers.  [R14-proven: 112 us]
// Wave: 16 rows x ALL 64 protos (acc = 16 VGPR; selection wave-complete).
// A: wave-private depth-3 LDS slices, 2 x global_load_lds/chunk, XOR-granule
//    source swizzle, counted vmcnt(10). B: depth-2 register prefetch hi/lo.
// ---------------------------------------------------------------------------
__global__ __launch_bounds__(256) void sim_kernel(
    const float* __restrict__ query, const float* __restrict__ protos,
    const unsigned short* __restrict__ bhi_u, const unsigned short* __restrict__ blo_u,
    float* __restrict__ out, int* __restrict__ cnt, int* __restrict__ list) {
  __shared__ __align__(16) float Abuf[4][3][512];   // 24 KiB: [wave][depth][16r x 32k]
  __shared__ float4 wiSw[4][16];                    // per-wave weights+indices

  const int t = threadIdx.x;
  const int wid = t >> 6;
  const int l = t & 63;
  const int lr = l & 15;          // A/D row within wave's 16
  const int lg = l >> 4;          // k-group
  const int row0 = blockIdx.x * 64;
  const int wr0 = row0 + wid * 16;

  const int sgswz = ((l & 7) ^ (l >> 3)) << 4;
  const int srow = l >> 3;
  auto stage = [&](int cc) {
#pragma unroll
    for (int i = 0; i < 2; ++i) {
      const char* src = (const char*)query +
          (size_t)(wr0 + i * 8 + srow) * 2048 + cc * 128 + sgswz;
      gload_lds16(src, (char*)&Abuf[wid][cc % 3][0] + i * 1024);
    }
  };

  const bf16x8* bhp = (const bf16x8*)bhi_u;
  const bf16x8* blp = (const bf16x8*)blo_u;

  f32x4 acc[4] = {};
  float ss = 0.f;
  bf16x8 Bh[2][4], Bl[2][4];

  stage(0);
#pragma unroll
  for (int pt = 0; pt < 4; ++pt) {
    Bh[0][pt] = bhp[(size_t)(0 * 4 + pt) * 64 + l];
    Bl[0][pt] = blp[(size_t)(0 * 4 + pt) * 64 + l];
  }
  __builtin_amdgcn_sched_barrier(0);
  stage(1);
#pragma unroll
  for (int pt = 0; pt < 4; ++pt) {
    Bh[1][pt] = bhp[(size_t)(1 * 4 + pt) * 64 + l];
    Bl[1][pt] = blp[(size_t)(1 * 4 + pt) * 64 + l];
  }

  const int g0 = lg * 2;
  const int sw = lr & 7;
  const char* abase = (const char*)&Abuf[wid][0][0];

#define SIM_CHUNK(C, NV)                                                      \
  {                                                                           \
    asm volatile("s_waitcnt vmcnt(" #NV ")" ::: "memory");                    \
    __builtin_amdgcn_sched_barrier(0);                                        \
    if ((C) + 2 < 16) stage((C) + 2);                                         \
    const char* ab = abase + ((C) % 3) * 2048;                                \
    const float4 a0 = *(const float4*)(ab + lr * 128 + ((g0 ^ sw) << 4));     \
    const float4 a1 = *(const float4*)(ab + lr * 128 + (((g0 + 1) ^ sw) << 4)); \
    const float av[8] = {a0.x, a0.y, a0.z, a0.w, a1.x, a1.y, a1.z, a1.w};     \
    bf16x8 ahi, alo;                                                          \
    _Pragma("unroll")                                                         \
    for (int i = 0; i < 8; ++i) {                                             \
      const unsigned int u = __float_as_uint(av[i]);                          \
      const unsigned short h = (unsigned short)(u >> 16);                     \
      ahi[i] = (short)h;                                                      \
      alo[i] = (short)f2bf(av[i] - bf2f(h));                                  \
      ss += av[i] * av[i];                                                    \
    }                                                                         \
    const int bb = (C) & 1;                                                   \
    _Pragma("unroll")                                                         \
    for (int pt = 0; pt < 4; ++pt) {                                          \
      acc[pt] = __builtin_amdgcn_mfma_f32_16x16x32_bf16(ahi, Bh[bb][pt], acc[pt], 0, 0, 0); \
      acc[pt] = __builtin_amdgcn_mfma_f32_16x16x32_bf16(ahi, Bl[bb][pt], acc[pt], 0, 0, 0); \
      acc[pt] = __builtin_amdgcn_mfma_f32_16x16x32_bf16(alo, Bh[bb][pt], acc[pt], 0, 0, 0); \
    }                                                                         \
    if ((C) + 2 < 16) {                                                       \
      _Pragma("unroll")                                                       \
      for (int pt = 0; pt < 4; ++pt) {                                        \
        Bh[bb][pt] = bhp[(size_t)(((C) + 2) * 4 + pt) * 64 + l];              \
        Bl[bb][pt] = blp[(size_t)(((C) + 2) * 4 + pt) * 64 + l];              \
      }                                                                       \
    }                                                                         \
  }

  SIM_CHUNK(0, 10)  SIM_CHUNK(1, 10)  SIM_CHUNK(2, 10)  SIM_CHUNK(3, 10)
  SIM_CHUNK(4, 10)  SIM_CHUNK(5, 10)  SIM_CHUNK(6, 10)  SIM_CHUNK(7, 10)
  SIM_CHUNK(8, 10)  SIM_CHUNK(9, 10)  SIM_CHUNK(10, 10) SIM_CHUNK(11, 10)
  SIM_CHUNK(12, 10) SIM_CHUNK(13, 10) SIM_CHUNK(14, 10) SIM_CHUNK(15, 0)
#undef SIM_CHUNK

  // full per-row sumsq: lane l holds row lr's k-slice lg
  ss += __shfl_xor(ss, 16);
  ss += __shfl_xor(ss, 32);

  // ---- selection (wave-complete): D col(proto within pt)=lr, row=lg*4+e ----
#pragma unroll
  for (int e = 0; e < 4; ++e) {
    float v0 = -1e30f, v1 = -1e30f, v2 = -1e30f, v3 = -1e30f;
    int j0 = 0, j1 = 0, j2 = 0, j3 = 0;
#pragma unroll
    for (int pt = 0; pt < 4; ++pt)
      ins4f(acc[pt][e], pt * 16 + lr, v0, v1, v2, v3, j0, j1, j2, j3);
#pragma unroll
    for (int m = 1; m <= 8; m <<= 1) {   // butterfly within 16-lane group
      const float p0 = __shfl_xor(v0, m), p1 = __shfl_xor(v1, m);
      const float p2 = __shfl_xor(v2, m), p3 = __shfl_xor(v3, m);
      const int q0 = __shfl_xor(j0, m), q1 = __shfl_xor(j1, m);
      const int q2 = __shfl_xor(j2, m), q3 = __shfl_xor(j3, m);
      ins4f(p0, q0, v0, v1, v2, v3, j0, j1, j2, j3);
      ins4f(p1, q1, v0, v1, v2, v3, j0, j1, j2, j3);
      ins4f(p2, q2, v0, v1, v2, v3, j0, j1, j2, j3);
      ins4f(p3, q3, v0, v1, v2, v3, j0, j1, j2, j3);
    }
    const float ssr = __shfl(ss, lg * 4 + e);   // ss of row lg*4+e
    if (lr == 0) {
      const int row = lg * 4 + e;               // row within wave's 16
      const float qi = 1.0f / fmaxf(sqrtf(ssr), 1e-12f);
      const float s0 = v0 * qi, s1 = v1 * qi, s2 = v2 * qi, s3 = v3 * qi;
      const float e1 = expf(s1 - s0), e2 = expf(s2 - s0);
      const float inv = 1.0f / (1.0f + e1 + e2);
      wiSw[wid][row] = make_float4(inv, e1 * inv, e2 * inv,
                                   __int_as_float(j0 | (j1 << 6) | (j2 << 12)));
      if (s2 - s3 < TAU) {
        const int pos = atomicAdd(cnt, 1);
        if (pos < LISTCAP) list[pos] = wr0 + row;
      }
    }
  }
  // no barrier: wiSw[wid] written and read by the same wave (in-order LDS)

  // ---- epilogue: weighted gather of this wave's 16 rows ----
#pragma unroll 2
  for (int r = 0; r < 16; ++r) {
    const float4 wi = wiSw[wid][r];
    const int pack = __float_as_int(wi.w);
    const int i0 = pack & 63, i1 = (pack >> 6) & 63, i2 = (pack >> 12) & 63;
    const float* p0 = protos + (size_t)i0 * DIM;
    const float* p1 = protos + (size_t)i1 * DIM;
    const float* p2 = protos + (size_t)i2 * DIM;
    float* orow = out + (size_t)(wr0 + r) * DIM;
#pragma unroll
    for (int h = 0; h < 2; ++h) {
      const int col = h * 256 + l * 4;
      const float4 x = *(const float4*)(p0 + col);
      const float4 y = *(const float4*)(p1 + col);
      const float4 z = *(const float4*)(p2 + col);
      float4 res;
      res.x = wi.x * x.x + wi.y * y.x + wi.z * z.x;
      res.y = wi.x * x.y + wi.y * y.y + wi.z * z.y;
      res.z = wi.x * x.z + wi.y * y.z + wi.z * z.z;
      res.w = wi.x * x.w + wi.y * y.w + wi.z * z.w;
      *(float4*)(orow + col) = res;
    }
  }
}

// ---------------------------------------------------------------------------
// Kernel 3: fp64 refine of compacted near-tie rows. One wave per row.
// ---------------------------------------------------------------------------
__global__ __launch_bounds__(256) void refine_kernel(
    const float* __restrict__ query, const float* __restrict__ protos,
    const float* __restrict__ ptw, const double* __restrict__ inv64,
    const int* __restrict__ cnt, const int* __restrict__ list,
    float* __restrict__ out) {
  const int n = min(*cnt, LISTCAP);
  const int lane = threadIdx.x & 63;
  const int gw = blockIdx.x * 4 + (threadIdx.x >> 6);

  for (int i = gw; i < n; i += RFB * 4) {
    const int row = list[i];
    const float* q = query + (size_t)row * DIM;
    double a0 = 0.0, a1 = 0.0, a2 = 0.0, a3 = 0.0;
    float qs = 0.f;
#pragma unroll 4
    for (int k = 0; k < DIM; k += 4) {
      const float4 qv = *(const float4*)(q + k);
      a0 = fma((double)qv.x, (double)ptw[(size_t)(k + 0) * NP + lane], a0);
      a1 = fma((double)qv.y, (double)ptw[(size_t)(k + 1) * NP + lane], a1);
      a2 = fma((double)qv.z, (double)ptw[(size_t)(k + 2) * NP + lane], a2);
      a3 = fma((double)qv.w, (double)ptw[(size_t)(k + 3) * NP + lane], a3);
      qs += qv.x * qv.x + qv.y * qv.y + qv.z * qv.z + qv.w * qv.w;
    }
    const double sim = (a0 + a1 + a2 + a3) * inv64[lane];

    double b0 = sim, b1 = -1e300, b2 = -1e300;
    int k0 = lane, k1 = 0, k2 = 0;
#pragma unroll
    for (int m = 1; m <= 32; m <<= 1) {
      const double p0 = __shfl_xor(b0, m), p1 = __shfl_xor(b1, m),
                   p2 = __shfl_xor(b2, m);
      const int q0 = __shfl_xor(k0, m), q1 = __shfl_xor(k1, m),
                q2 = __shfl_xor(k2, m);
      ins3d(p0, q0, b0, b1, b2, k0, k1, k2);
      ins3d(p1, q1, b0, b1, b2, k0, k1, k2);
      ins3d(p2, q2, b0, b1, b2, k0, k1, k2);
    }
    const double qi = 1.0 / fmax(sqrt((double)qs), 1e-12);
    const double s0 = b0 * qi, s1 = b1 * qi, s2 = b2 * qi;
    const double e1 = exp(s1 - s0), e2 = exp(s2 - s0);
    const double inv = 1.0 / (1.0 + e1 + e2);
    const double w0 = inv, w1 = e1 * inv, w2 = e2 * inv;
    const float* p0r = protos + (size_t)k0 * DIM;
    const float* p1r = protos + (size_t)k1 * DIM;
    const float* p2r = protos + (size_t)k2 * DIM;
#pragma unroll
    for (int u = 0; u < 2; ++u) {
      const int col = u * 256 + lane * 4;
      const float4 x = *(const float4*)(p0r + col);
      const float4 y = *(const float4*)(p1r + col);
      const float4 z = *(const float4*)(p2r + col);
      float4 res;
      res.x = (float)(w0 * x.x + w1 * y.x + w2 * z.x);
      res.y = (float)(w0 * x.y + w1 * y.y + w2 * z.y);
      res.z = (float)(w0 * x.z + w1 * y.z + w2 * z.z);
      res.w = (float)(w0 * x.w + w1 * y.w + w2 * z.w);
      *(float4*)(out + (size_t)row * DIM + col) = res;
    }
  }
}

extern "C" void kernel_launch(void* const* d_in, const int* in_sizes, int n_in,
                              void* d_out, int out_size, void* d_ws, size_t ws_size,
                              hipStream_t stream) {
  const float* query = (const float*)d_in[0];
  const float* protos = (const float*)d_in[1];
  float* out = (float*)d_out;
  float* ptw = (float*)((char*)d_ws + WS_PTW);
  unsigned short* bhi = (unsigned short*)((char*)d_ws + WS_BHI);
  unsigned short* blo = (unsigned short*)((char*)d_ws + WS_BLO);
  double* inv64 = (double*)((char*)d_ws + WS_INV64);
  int* cnt = (int*)((char*)d_ws + WS_CNT);
  int* list = (int*)((char*)d_ws + WS_LIST);

  const int nrows = in_sizes[0] / DIM;

  hipLaunchKernelGGL(prep_all_kernel, dim3(16), dim3(256), 0, stream,
                     protos, ptw, bhi, blo, inv64, cnt);
  hipLaunchKernelGGL(sim_kernel, dim3(nrows / 64), dim3(256), 0, stream,
                     query, protos, bhi, blo, out, cnt, list);
  hipLaunchKernelGGL(refine_kernel, dim3(RFB), dim3(256), 0, stream,
                     query, protos, ptw, inv64, cnt, list, out);
}